// Round 10
// baseline (167.446 us; speedup 1.0000x reference)
//
#include <hip/hip_runtime.h>
#include <hip/hip_bf16.h>
#include <stdint.h>

#define NV   65536   // active voxels
#define KOFF 27      // kernel offsets
#define CIN  128
#define COUT 128

typedef __bf16 bf16x8 __attribute__((ext_vector_type(8)));
typedef float  f32x4  __attribute__((ext_vector_type(4)));

__device__ __forceinline__ void async_copy16(void* lds, const void* g) {
    __builtin_amdgcn_global_load_lds(
        (const __attribute__((address_space(1))) void*)g,
        (__attribute__((address_space(3))) void*)lds,
        16, 0, 0);
}

// ---- fused prep kernel --------------------------------------------------
// Jobs partitioned by blockIdx range (mutually independent; nbr memset to
// 0xFF by a prior hipMemsetAsync node on the same stream):
//   A [0, 4097)    : features f32 -> bf16 x8 (row NV zeroed)
//   B [4097, 4313) : weight f32 [K][cin][cout] -> bf16 fragment-major,
//                    s-major (s = k*4+ks in [0,108)):
//                    chunk c = s*512 + wv*128 + nt*64 + lane, holding
//                    B[cout=wv*32+nt*16+(lane&15)][cin=ks*32+(lane>>4)*8+j]
//   S [4313, 6041) : rulebook scatter x4: nbr[k][out[p]] = in[p]
#define JOB_A_BLOCKS 4097
#define JOB_B_BLOCKS 216    // 108*512 chunks / 256
#define JOB_S_BLOCKS 1728   // 27*65536/4/256

__global__ void k_prep_all(const float* __restrict__ f,
                           uint4* __restrict__ fb4,
                           const float* __restrict__ w,
                           uint4* __restrict__ wfrag4,
                           const int4* __restrict__ in4,
                           const int4* __restrict__ out4,
                           int* __restrict__ nbr) {
    const int b = blockIdx.x;
    const int t = threadIdx.x;
    if (b < JOB_A_BLOCKS) {
        // ---- job A: feature cast x8 ----
        int i = b * 256 + t;
        int total8  = (NV + 1) * CIN / 8;
        int nvalid8 = NV * CIN / 8;
        if (i >= total8) return;
        union { uint4 u; __hip_bfloat16 h[8]; } p;
        if (i < nvalid8) {
            const float4* f4 = (const float4*)f;
            float4 a = f4[i * 2];
            float4 c = f4[i * 2 + 1];
            p.h[0] = __float2bfloat16(a.x);
            p.h[1] = __float2bfloat16(a.y);
            p.h[2] = __float2bfloat16(a.z);
            p.h[3] = __float2bfloat16(a.w);
            p.h[4] = __float2bfloat16(c.x);
            p.h[5] = __float2bfloat16(c.y);
            p.h[6] = __float2bfloat16(c.z);
            p.h[7] = __float2bfloat16(c.w);
        } else {
            p.u = make_uint4(0, 0, 0, 0);   // zero row NV
        }
        fb4[i] = p.u;
    } else if (b < JOB_A_BLOCKS + JOB_B_BLOCKS) {
        // ---- job B: weight -> s-major fragment layout ----
        int c    = (b - JOB_A_BLOCKS) * 256 + t;   // chunk index
        int lane = c & 63;
        int nt   = (c >> 6) & 1;
        int wv   = (c >> 7) & 3;
        int s    = c >> 9;
        int ks   = s & 3;
        int k    = s >> 2;
        int cout = wv * 32 + nt * 16 + (lane & 15);
        int cin0 = ks * 32 + (lane >> 4) * 8;
        const float* wk = w + k * 16384;
        union { uint4 u; __hip_bfloat16 h[8]; } p;
        #pragma unroll
        for (int j = 0; j < 8; ++j)
            p.h[j] = __float2bfloat16(wk[(cin0 + j) * 128 + cout]);
        wfrag4[c] = p.u;
    } else {
        // ---- job S: rulebook scatter x4 (out_idx sorted -> near-coalesced) ----
        int i = (b - JOB_A_BLOCKS - JOB_B_BLOCKS) * 256 + t;
        int k = i >> 14;                   // / (NV/4)
        int4 ii = in4[i];
        int4 oo = out4[i];
        int* nb = nbr + k * (NV + 1);      // slot NV = dummy for padded pairs
        nb[oo.x] = ii.x;
        nb[oo.y] = ii.y;
        nb[oo.z] = ii.z;
        nb[oo.w] = ii.w;
    }
}

// ---- main gather-GEMM kernel -------------------------------------------
// block = 512 thr (8 waves, 2x4: wave = 64 rows x 32 cols), grid 512,
// single-buffer A (32 KB LDS) -> 2 blocks/CU = 16 waves/CU = 4 waves/SIMD
// (double R5's wave pool; cross-block/wave overlap hides stage+barrier).
// Per offset: stage gathered A via global_load_lds x16 (4 iters/thread),
// barrier, 4 ks-steps of mfma 16x16x32 with B from a register ks-ring
// (2x2 uint4; safe — no A staging outstanding during compute; ring carries
// B(k+1,ks0) across the offset boundary), barrier. XOR-chunk LDS swizzle
// keeps reads conflict-free. nbr(k+1) prefetched during compute(k).
__global__ __launch_bounds__(512, 4)
void sp_conv_main(const __hip_bfloat16* __restrict__ feats,
                  const uint4* __restrict__ wfrag,
                  const int* __restrict__ nbr,
                  const float* __restrict__ bias,
                  float* __restrict__ out) {
    __shared__ unsigned char smA[32768];   // single 32 KB A buffer

    const int t   = threadIdx.x;
    const int bid = blockIdx.x;
    // XCD swizzle: consecutive 64-tile ranges per XCD for L2 gather locality
    const int tile0 = ((bid & 7) * 64 + (bid >> 3)) * 128;

    const int w    = t >> 6;          // wave [0,8)
    const int lane = t & 63;
    const int lr   = lane & 15;
    const int quad = lane >> 4;
    const int m0   = (w >> 2) * 64;   // row half
    const int n0   = (w & 3) * 32;    // col quarter

    // staging-side mapping: 512 thr x 16 B = 8 KB (32 rows) per pass, 4 passes.
    // LDS slot (row = i*32 + t/16, physchunk = t&15) holds global 16B chunk
    // c = (t&15) ^ (row&15)
    const int srow   = t >> 4;                       // [0,32)
    const int sbyte  = ((t & 15) ^ (srow & 15)) * 16;

    f32x4 acc[4][2] = {};  // 32 VGPRs

    const unsigned char* featsB = (const unsigned char*)feats;
    const uint4* wfp = wfrag + (w & 3) * 128 + lane;

    // nbr rows for k=0 (4 per thread)
    int arows[4];
    {
        const int* nbr0 = nbr + tile0;
        #pragma unroll
        for (int i = 0; i < 4; ++i) arows[i] = nbr0[i * 32 + srow];
    }
    // B ring: group s lives in bb[s&1]; preload s=0
    uint4 bb[2][2];
    #pragma unroll
    for (int nt = 0; nt < 2; ++nt) bb[0][nt] = wfp[nt * 64];

    for (int k = 0; k < KOFF; ++k) {
        // stage A(k): 4 global_load_lds x16 per thread
        #pragma unroll
        for (int i = 0; i < 4; ++i) {
            unsigned ar = min((unsigned)arows[i], (unsigned)NV);  // -1 -> zero row
            async_copy16(smA + i * 8192 + t * 16,
                         featsB + (size_t)ar * 256 + sbyte);
        }
        // prefetch nbr rows for k+1 (used after next stage barrier)
        if (k + 1 < KOFF) {
            const int* nbrn = nbr + (k + 1) * (NV + 1) + tile0;
            #pragma unroll
            for (int i = 0; i < 4; ++i) arows[i] = nbrn[i * 32 + srow];
        }
        __syncthreads();   // drain staging; LDS tile ready

        // compute: B group s feeds ks, group s+1 loads (only vmem in flight);
        // at ks=3 this loads B(k+1, ks=0) -> ring carries across offsets.
        #pragma unroll
        for (int ks = 0; ks < 4; ++ks) {
            const int s = k * 4 + ks;
            if (s + 1 < 4 * KOFF) {
                const uint4* wfn = wfp + (size_t)(s + 1) * 512;
                #pragma unroll
                for (int nt = 0; nt < 2; ++nt)
                    bb[(ks + 1) & 1][nt] = wfn[nt * 64];
            }
            #pragma unroll
            for (int mt = 0; mt < 4; ++mt) {
                int row = m0 + mt * 16 + lr;          // row & 15 == lr
                bf16x8 af = *(const bf16x8*)(smA + row * 256 +
                                             (((ks * 4 + quad) ^ lr) * 16));
                #pragma unroll
                for (int nt = 0; nt < 2; ++nt)
                    acc[mt][nt] = __builtin_amdgcn_mfma_f32_16x16x32_bf16(
                        af, *(const bf16x8*)&bb[ks & 1][nt],
                        acc[mt][nt], 0, 0, 0);
            }
        }
        __syncthreads();   // protect smA before next stage overwrites
    }

    // epilogue: C/D layout col = lane&15, row = quad*4 + reg
    float bv[2];
    #pragma unroll
    for (int nt = 0; nt < 2; ++nt) bv[nt] = bias[n0 + nt * 16 + lr];

    #pragma unroll
    for (int mt = 0; mt < 4; ++mt) {
        #pragma unroll
        for (int nt = 0; nt < 2; ++nt) {
            #pragma unroll
            for (int r = 0; r < 4; ++r) {
                int grow = tile0 + m0 + mt * 16 + quad * 4 + r;
                out[(size_t)grow * COUT + n0 + nt * 16 + lr] =
                    acc[mt][nt][r] + bv[nt];
            }
        }
    }
}

// ---- launch -------------------------------------------------------------

extern "C" void kernel_launch(void* const* d_in, const int* in_sizes, int n_in,
                              void* d_out, int out_size, void* d_ws, size_t ws_size,
                              hipStream_t stream) {
    const float* features = (const float*)d_in[0];   // [N,128] f32
    const float* weight   = (const float*)d_in[1];   // [27,128,128] f32
    const float* bias     = (const float*)d_in[2];   // [128] f32
    const int*   in_idx   = (const int*)d_in[3];     // [27,N] i32
    const int*   out_idx  = (const int*)d_in[4];     // [27,N] i32
    float* out = (float*)d_out;                      // [N,128] f32

    uint8_t* ws = (uint8_t*)d_ws;
    size_t off = 0;
    __hip_bfloat16* feats_bf = (__hip_bfloat16*)(ws + off);       // (N+1)*128*2
    off += (size_t)(NV + 1) * CIN * 2;
    off = (off + 255) & ~(size_t)255;
    uint4* wfrag = (uint4*)(ws + off);                            // 108*512*16 B
    off += (size_t)108 * 512 * 16;
    off = (off + 255) & ~(size_t)255;
    int* nbr = (int*)(ws + off);                                  // 27*(NV+1)*4

    // init nbr to 0xFFFFFFFF (-1 = "no neighbor"; main clamps to zero row)
    hipMemsetAsync(nbr, 0xFF, (size_t)KOFF * (NV + 1) * 4, stream);

    // fused prep: feature cast + weight fragment-permute + rulebook scatter
    k_prep_all<<<JOB_A_BLOCKS + JOB_B_BLOCKS + JOB_S_BLOCKS, 256, 0, stream>>>(
        features, (uint4*)feats_bf, weight, wfrag,
        (const int4*)in_idx, (const int4*)out_idx, nbr);

    // main gather-GEMM: 512 tiles of 128 rows, 512-thread blocks
    sp_conv_main<<<NV / 128, 512, 0, stream>>>(feats_bf, wfrag, nbr, bias, out);
}